// Round 10
// baseline (513.898 us; speedup 1.0000x reference)
//
#include <hip/hip_runtime.h>
#include <hip/hip_bf16.h>
#include <stdint.h>

#define CDIM 256
#define HH 36
#define WW 36
#define NPX 1296          // 36*36
#define PW 38             // padded width (1-px halo)
#define PPIX 1444         // 38*38
#define NIMG 32
#define NROI 512
#define FCK 4096
#define EPS_BN 1e-5f
#define SBLK 324          // stats blocks (41472 rows / 324 = 128 rows/block)
#define NWC (9*CDIM*CDIM) // weights per conv layer

typedef __bf16 bf16;
typedef __bf16 bf16x8 __attribute__((ext_vector_type(8)));
typedef float f32x4 __attribute__((ext_vector_type(4)));
typedef unsigned short us8 __attribute__((ext_vector_type(8)));

// async global->LDS, 16B per lane; LDS dest is wave-uniform base + lane*16
#define GLD16(g, l) __builtin_amdgcn_global_load_lds( \
    (__attribute__((address_space(1))) void*)(g),     \
    (__attribute__((address_space(3))) void*)(l), 16, 0, 0)

// ---------------- zero only the 1-px halo of xp0/xp1 (replaces 47MB memset)
__global__ void k_halo(bf16* __restrict__ xp0, bf16* __restrict__ xp1) {
  int n = blockIdx.x, a = blockIdx.y, t = threadIdx.x;
  bf16* base = (a ? xp1 : xp0) + (size_t)n * PPIX * CDIM;
  us8 z = {0, 0, 0, 0, 0, 0, 0, 0};
  // top (h=0) and bottom (h=37) rows: 2 * 38*256 elems
  for (int i = t; i < (2 * PW * CDIM) / 8; i += 256) {
    int half = (PW * CDIM) / 8;
    int row = (i < half) ? 0 : 37;
    int off = (i < half) ? i : i - half;
    *(us8*)(base + (size_t)row * PW * CDIM + off * 8) = z;
  }
  // left (w=0) and right (w=37) columns for h=1..36
  for (int i = t; i < (2 * 36 * CDIM) / 8; i += 256) {
    int half = (36 * CDIM) / 8;
    int side = (i < half) ? 0 : 37;
    int j = (i < half) ? i : i - half;
    int h = 1 + (j >> 5);          // 32 us8 per (h,w) cell row of 256 ch
    int cv = j & 31;
    *(us8*)(base + ((size_t)h * PW + side) * CDIM + cv * 8) = z;
  }
}

// ---------------- merged prep: 3x conv weight reorder + fc weight cast
__global__ void k_prep(const float* __restrict__ w0, const float* __restrict__ w1,
                       const float* __restrict__ w2, const float* __restrict__ fcw,
                       bf16* __restrict__ wb, bf16* __restrict__ fwb) {
  int i = blockIdx.x * 256 + threadIdx.x;
  if (i < 3 * NWC) {
    int l = i / NWC, r = i - l * NWC;
    const float* ws = (l == 0) ? w0 : (l == 1) ? w1 : w2;
    int tap = r / (CDIM * CDIM);
    int rem = r - tap * (CDIM * CDIM);
    int co = rem >> 8, ci = rem & 255;
    wb[i] = (bf16)ws[(size_t)(co * CDIM + ci) * 9 + tap];
  } else {
    int j = i - 3 * NWC;
    if (j < CDIM * FCK) fwb[j] = (bf16)fcw[j];
  }
}

// ---------------- feat NCHW f32 -> padded NHWC bf16 via LDS transpose
__global__ void k_convert(const float* __restrict__ feat, bf16* __restrict__ xp) {
  __shared__ bf16 tile[CDIM * 38];
  int h = blockIdx.x, n = blockIdx.y, t = threadIdx.x;
  const float* src = feat + (size_t)n * CDIM * NPX + (size_t)h * WW;
#pragma unroll 4
  for (int i = 0; i < 36; ++i) {
    int f = i * 256 + t;
    int c = (int)(((unsigned)f * 7282u) >> 18);  // f/36
    int w = f - c * 36;
    tile[c * 38 + w] = (bf16)src[(size_t)c * NPX + w];
  }
  __syncthreads();
  bf16* dst = xp + (size_t)n * PPIX * CDIM + ((h + 1) * PW + 1) * CDIM + t;
#pragma unroll 4
  for (int w = 0; w < 36; ++w) dst[w * CDIM] = tile[t * 38 + w];
}

// ---------------- conv3x3 implicit GEMM, 128co x 128px tile, bf16 MFMA
// r2 XCD swizzle: XCD k owns images {k,k+8,k+16,k+24}, both cot halves
// (4.2 MB working set per XCD fits 4 MB L2; FETCH 17MB verified r9).
__global__ __launch_bounds__(256) void k_conv(
    const bf16* __restrict__ xp, const bf16* __restrict__ wb,
    bf16* __restrict__ y)
{
  __shared__ __align__(16) bf16 ldsA[2][4096];
  __shared__ __align__(16) bf16 ldsB[2][4096];
  const int tid = threadIdx.x;
  const int wave = tid >> 6, lane = tid & 63;

  const int B = blockIdx.x;
  const int xcd = B & 7, idx = B >> 3;        // idx 0..87
  const int ng = idx / 22, inner = idx - ng * 22;
  const int n = (ng << 3) + xcd;              // image 0..31
  const int cot = inner / 11, pxt = inner - cot * 11;

  // staging addressing (XOR chunk swizzle pre-applied to global source)
  const int q = lane >> 2;
  const int gsw = (lane & 3) ^ ((q >> 1) & 3);
  const int rA = wave * 32 + q;
  const bf16* aS0 = wb + (size_t)(cot * 128 + rA) * CDIM + gsw * 8;
  const bf16* aS1 = aS0 + 16 * CDIM;
  int pxa = pxt * 128 + rA;       if (pxa > NPX - 1) pxa = NPX - 1;
  int pxb = pxt * 128 + rA + 16;  if (pxb > NPX - 1) pxb = NPX - 1;
  const int ha = pxa / 36, wa = pxa - ha * 36;
  const int hb = pxb / 36, wbv = pxb - hb * 36;
  const bf16* bS0 = xp + (size_t)n * (PPIX * CDIM) + ((ha + 1) * PW + (wa + 1)) * CDIM + gsw * 8;
  const bf16* bS1 = xp + (size_t)n * (PPIX * CDIM) + ((hb + 1) * PW + (wbv + 1)) * CDIM + gsw * 8;

  // fragment-read addressing
  const int fr = lane & 15, fg = lane >> 4;
  const int fsw = (fg ^ ((fr >> 1) & 3)) * 8;
  const int wco = wave >> 1, wpx = wave & 1;
  const int aoff = (wco * 64 + fr) * 32 + fsw;
  const int boff = (wpx * 64 + fr) * 32 + fsw;

  f32x4 acc[4][4];
#pragma unroll
  for (int i = 0; i < 4; ++i)
#pragma unroll
    for (int j = 0; j < 4; ++j) acc[i][j] = f32x4{0.f, 0.f, 0.f, 0.f};

  { // prologue: stage k=0 (tap 0: dh=-1,dw=-1, ci0=0)
    const int xoff = -(PW + 1) * CDIM;
    GLD16(aS0, &ldsA[0][wave * 1024]);
    GLD16(aS1, &ldsA[0][wave * 1024 + 512]);
    GLD16(bS0 + xoff, &ldsB[0][wave * 1024]);
    GLD16(bS1 + xoff, &ldsB[0][wave * 1024 + 512]);
  }

#pragma unroll 2
  for (int k = 0; k < 72; ++k) {
    const int buf = k & 1;
    __syncthreads();
    if (k + 1 < 72) {
      const int kn = k + 1;
      const int tap = kn >> 3, ci0 = (kn & 7) << 5;
      const int dh = tap / 3 - 1, dw = tap - (tap / 3) * 3 - 1;
      const int woff = tap * (CDIM * CDIM) + ci0;
      const int xoff = (dh * PW + dw) * CDIM + ci0;
      const int nb = buf ^ 1;
      GLD16(aS0 + woff, &ldsA[nb][wave * 1024]);
      GLD16(aS1 + woff, &ldsA[nb][wave * 1024 + 512]);
      GLD16(bS0 + xoff, &ldsB[nb][wave * 1024]);
      GLD16(bS1 + xoff, &ldsB[nb][wave * 1024 + 512]);
    }
    bf16x8 av[4], bv[4];
#pragma unroll
    for (int i = 0; i < 4; ++i) av[i] = *(const bf16x8*)&ldsA[buf][aoff + i * 512];
#pragma unroll
    for (int j = 0; j < 4; ++j) bv[j] = *(const bf16x8*)&ldsB[buf][boff + j * 512];
#pragma unroll
    for (int i = 0; i < 4; ++i)
#pragma unroll
      for (int j = 0; j < 4; ++j)
        acc[i][j] = __builtin_amdgcn_mfma_f32_16x16x32_bf16(av[i], bv[j], acc[i][j], 0, 0, 0);
  }

  // epilogue: C/D layout col(px)=lane&15, row(co)=(lane>>4)*4+reg
#pragma unroll
  for (int j = 0; j < 4; ++j) {
    const int px = pxt * 128 + wpx * 64 + j * 16 + fr;
    if (px < NPX) {
      bf16* dst = y + ((size_t)n * NPX + px) * CDIM + cot * 128 + wco * 64 + fg * 4;
#pragma unroll
      for (int i = 0; i < 4; ++i) {
        f32x4 a = acc[i][j];
        union { bf16 b4[4]; ushort4 u4; } pk;
        pk.b4[0] = (bf16)a[0]; pk.b4[1] = (bf16)a[1];
        pk.b4[2] = (bf16)a[2]; pk.b4[3] = (bf16)a[3];
        *(ushort4*)(dst + i * 16) = pk.u4;
      }
    }
  }
}

// ---------------- per-channel sum/sumsq over bf16 y [41472][256]: 324 partial slots
__global__ void k_statsb(const bf16* __restrict__ y, float* __restrict__ psum,
                         float* __restrict__ psq) {
  __shared__ float lsum[8][256];
  __shared__ float lsq[8][256];
  int t = threadIdx.x;
  int c8 = (t & 31) * 8, rg = t >> 5;           // 32 channel-chunks x 8 row-groups
  size_t row0 = (size_t)blockIdx.x * 128 + rg;
  float s[8], qq[8];
#pragma unroll
  for (int k = 0; k < 8; ++k) { s[k] = 0.f; qq[k] = 0.f; }
  for (int i = 0; i < 16; ++i) {
    const bf16* p = y + (row0 + (size_t)i * 8) * CDIM + c8;
    union { bf16 b8[8]; us8 u; } v;
    v.u = *(const us8*)p;
#pragma unroll
    for (int k = 0; k < 8; ++k) {
      float f = (float)v.b8[k];
      s[k] += f; qq[k] += f * f;
    }
  }
#pragma unroll
  for (int k = 0; k < 8; ++k) { lsum[rg][c8 + k] = s[k]; lsq[rg][c8 + k] = qq[k]; }
  __syncthreads();
  float ss = 0.f, sq2 = 0.f;
#pragma unroll
  for (int g = 0; g < 8; ++g) { ss += lsum[g][t]; sq2 += lsq[g][t]; }
  psum[blockIdx.x * 256 + t] = ss;
  psq[blockIdx.x * 256 + t] = sq2;
}

// ---------------- sum partial slots + finalize BN coefficients (1 block, 1024 thr)
__global__ __launch_bounds__(1024) void k_sredfin(
    const float* __restrict__ psum, const float* __restrict__ psq,
    const float* __restrict__ g, const float* __restrict__ b,
    float* __restrict__ sc, float* __restrict__ sh, float invn) {
  __shared__ float ls[4][256], lq[4][256];
  int t = threadIdx.x;
  int c = t & 255, gi = t >> 8;
  float s = 0.f, q = 0.f;
  for (int i = gi; i < SBLK; i += 4) { s += psum[i * 256 + c]; q += psq[i * 256 + c]; }
  ls[gi][c] = s; lq[gi][c] = q;
  __syncthreads();
  if (gi == 0) {
    s = ls[0][c] + ls[1][c] + ls[2][c] + ls[3][c];
    q = lq[0][c] + lq[1][c] + lq[2][c] + lq[3][c];
    float m = s * invn;
    float v = q * invn - m * m;
    float sca = g[c] * rsqrtf(v + EPS_BN);
    sc[c] = sca;
    sh[c] = b[c] - m * sca;
  }
}

// ---------------- y bf16 NHWC -> BN+ReLU -> padded NHWC bf16 (interior only)
__global__ void k_normalize(const bf16* __restrict__ y, const float* __restrict__ sc,
                            const float* __restrict__ sh, bf16* __restrict__ xp) {
  int t = threadIdx.x;
  int n = blockIdx.y;
  int px = blockIdx.x * 8 + (t >> 5);
  int c8 = (t & 31) * 8;
  const bf16* srcp = y + ((size_t)n * NPX + px) * CDIM + c8;
  union { bf16 b8[8]; us8 u; } in, outp;
  in.u = *(const us8*)srcp;
  int h = px / 36, w = px - h * 36;
#pragma unroll
  for (int i = 0; i < 8; ++i) {
    float v = (float)in.b8[i];
    outp.b8[i] = (bf16)fmaxf(v * sc[c8 + i] + sh[c8 + i], 0.f);
  }
  *(us8*)(xp + (size_t)n * PPIX * CDIM + ((h + 1) * PW + (w + 1)) * CDIM + c8) = outp.u;
}

// ---------------- hat-function cumulative integral: H(u) = int_{-inf}^{u} max(0,1-|x|) dx
__device__ __forceinline__ float hatH(float u) {
  u = fminf(fmaxf(u, -1.f), 1.f);
  float p = u + 1.f;
  return (u < 0.f) ? 0.5f * p * p : 0.5f + u * (1.f - 0.5f * u);
}

// ---------------- PrRoI pool, direct separable form; grid (roi, ch-half, i-pair)
__global__ __launch_bounds__(128) void k_pool(
    const bf16* __restrict__ y, const float* __restrict__ sc,
    const float* __restrict__ sh, const float* __restrict__ props,
    bf16* __restrict__ rf) {
  int roi = blockIdx.x;
  int c = blockIdx.y * 128 + threadIdx.x;
  int i0 = blockIdx.z * 2;                  // i-cells {i0, i0+1}
  int b = roi >> 4;
  const float* pr = props + (size_t)roi * 4;
  float x1 = pr[0] * 20.f, yy1 = pr[1] * 20.f;
  float x2 = (pr[0] + pr[2]) * 20.f, yy2 = (pr[1] + pr[3]) * 20.f;
  float bw = (x2 - x1) * 0.25f, bh = (yy2 - yy1) * 0.25f;

  float xs[5];
#pragma unroll
  for (int j = 0; j < 5; ++j) xs[j] = fminf(fmaxf(x1 + bw * j, 0.f), 35.f);
  float wxv[4][5];
  int sx[4];
#pragma unroll
  for (int j = 0; j < 4; ++j) {
    float a = xs[j], bb = xs[j + 1];
    int s = (int)floorf(a);
    sx[j] = s;
#pragma unroll
    for (int k = 0; k < 5; ++k) {
      float w = (float)(s + k);
      wxv[j][k] = hatH(bb - w) - hatH(a - w);
    }
  }
  float wyv[2][5];
  int sy[2];
#pragma unroll
  for (int ii = 0; ii < 2; ++ii) {
    float ay = fminf(fmaxf(yy1 + bh * (i0 + ii), 0.f), 35.f);
    float by = fminf(fmaxf(yy1 + bh * (i0 + ii + 1), 0.f), 35.f);
    int tt = (int)floorf(ay);
    sy[ii] = tt;
#pragma unroll
    for (int k = 0; k < 5; ++k) {
      float w = (float)(tt + k);
      wyv[ii][k] = hatH(by - w) - hatH(ay - w);
    }
  }

  float s_ = sc[c], t_ = sh[c];
  const bf16* yb = y + (size_t)b * NPX * CDIM + c;
  float acc[2][4];
#pragma unroll
  for (int ii = 0; ii < 2; ++ii)
#pragma unroll
    for (int j = 0; j < 4; ++j) acc[ii][j] = 0.f;

#pragma unroll
  for (int ii = 0; ii < 2; ++ii) {
#pragma unroll
    for (int ky = 0; ky < 5; ++ky) {
      float wy = wyv[ii][ky];
      if (wy == 0.f) continue;            // block-uniform branch
      int h = sy[ii] + ky; if (h > 35) h = 35;
      const bf16* rowp = yb + h * (WW * CDIM);
#pragma unroll
      for (int j = 0; j < 4; ++j) {
        float rd = 0.f;
#pragma unroll
        for (int kx = 0; kx < 5; ++kx) {
          int w = sx[j] + kx; if (w > 35) w = 35;
          float f = fmaxf((float)rowp[w * CDIM] * s_ + t_, 0.f);
          rd += wxv[j][kx] * f;
        }
        acc[ii][j] += wy * rd;
      }
    }
  }

  float area = bw * bh;
  float inv = area > 1e-8f ? 1.f / area : 0.f;
  bf16 outv[8];
#pragma unroll
  for (int ii = 0; ii < 2; ++ii)
#pragma unroll
    for (int j = 0; j < 4; ++j)
      outv[ii * 4 + j] = (bf16)(acc[ii][j] * inv);
  bf16* dst = rf + (size_t)roi * FCK + c * 16 + i0 * 4;
  *(us8*)dst = *(us8*)&outv[0];
}

// ---------------- fc GEMM: fcp[ks][roi][o] = partial, split-K=8, MFMA, no atomics
__global__ __launch_bounds__(256) void k_fcgemm(const bf16* __restrict__ rf,
                                                const bf16* __restrict__ fw,
                                                float* __restrict__ fcp) {
  int tid = threadIdx.x, wave = tid >> 6, lane = tid & 63;
  int wo = wave >> 1, wr = wave & 1;
  int rt = blockIdx.x, ot = blockIdx.y, ks = blockIdx.z;
  int fr = lane & 15, fg = lane >> 4;
  const bf16* ap = fw + (size_t)(ot * 64 + wo * 32 + fr) * FCK + ks * 512 + fg * 8;
  const bf16* bp = rf + (size_t)(rt * 64 + wr * 32 + fr) * FCK + ks * 512 + fg * 8;
  f32x4 acc[2][2];
#pragma unroll
  for (int i = 0; i < 2; ++i)
#pragma unroll
    for (int j = 0; j < 2; ++j) acc[i][j] = f32x4{0.f, 0.f, 0.f, 0.f};
#pragma unroll 4
  for (int k = 0; k < 512; k += 32) {
    bf16x8 a0 = *(const bf16x8*)(ap + k);
    bf16x8 a1 = *(const bf16x8*)(ap + 16 * FCK + k);
    bf16x8 b0 = *(const bf16x8*)(bp + k);
    bf16x8 b1 = *(const bf16x8*)(bp + 16 * FCK + k);
    acc[0][0] = __builtin_amdgcn_mfma_f32_16x16x32_bf16(a0, b0, acc[0][0], 0, 0, 0);
    acc[0][1] = __builtin_amdgcn_mfma_f32_16x16x32_bf16(a0, b1, acc[0][1], 0, 0, 0);
    acc[1][0] = __builtin_amdgcn_mfma_f32_16x16x32_bf16(a1, b0, acc[1][0], 0, 0, 0);
    acc[1][1] = __builtin_amdgcn_mfma_f32_16x16x32_bf16(a1, b1, acc[1][1], 0, 0, 0);
  }
#pragma unroll
  for (int i = 0; i < 2; ++i)
#pragma unroll
    for (int j = 0; j < 2; ++j) {
      int o = ot * 64 + wo * 32 + i * 16 + fg * 4;
      int r = rt * 64 + wr * 32 + j * 16 + fr;
      *(f32x4*)(fcp + ((size_t)ks * NROI + r) * CDIM + o) = acc[i][j];
    }
}

// ---------------- reduce split-K slabs: fcx[r][o] = sum_ks fcp[ks][r][o]
__global__ void k_fcred(const float* __restrict__ fcp, float* __restrict__ fcx) {
  int r = blockIdx.x, o = threadIdx.x;
  float s = 0.f;
#pragma unroll
  for (int ks = 0; ks < 8; ++ks) s += fcp[((size_t)ks * NROI + r) * CDIM + o];
  fcx[(size_t)r * CDIM + o] = s;
}

// ---------------- fc BN stats + finalize (1 block, 1024 thr)
__global__ __launch_bounds__(1024) void k_fcstatfin(
    const float* __restrict__ fcx, const float* __restrict__ g,
    const float* __restrict__ b, float* __restrict__ sc, float* __restrict__ sh) {
  __shared__ float ls[4][256], lq[4][256];
  int t = threadIdx.x, c = t & 255, gi = t >> 8;
  float s = 0.f, q = 0.f;
  for (int r = gi; r < NROI; r += 4) {
    float v = fcx[(size_t)r * CDIM + c];
    s += v; q += v * v;
  }
  ls[gi][c] = s; lq[gi][c] = q;
  __syncthreads();
  if (gi == 0) {
    s = ls[0][c] + ls[1][c] + ls[2][c] + ls[3][c];
    q = lq[0][c] + lq[1][c] + lq[2][c] + lq[3][c];
    float m = s * (1.f / 512.f);
    float vv = q * (1.f / 512.f) - m * m;
    float sca = g[c] * rsqrtf(vv + EPS_BN);
    sc[c] = sca;
    sh[c] = b[c] - m * sca;
  }
}

// ---------------- fc BN + ReLU + iou head
__global__ void k_iou(const float* __restrict__ fcx, const float* __restrict__ sc,
                      const float* __restrict__ sh, const float* __restrict__ iw,
                      const float* __restrict__ ib, float* __restrict__ out) {
  __shared__ float red[4];
  int roi = blockIdx.x, t = threadIdx.x;
  float v = fcx[(size_t)roi * CDIM + t];
  v = fmaxf(v * sc[t] + sh[t], 0.f) * iw[t];
#pragma unroll
  for (int o = 32; o > 0; o >>= 1) v += __shfl_down(v, o);
  if ((t & 63) == 0) red[t >> 6] = v;
  __syncthreads();
  if (t == 0) out[roi] = red[0] + red[1] + red[2] + red[3] + ib[0];
}

extern "C" void kernel_launch(void* const* d_in, const int* in_sizes, int n_in,
                              void* d_out, int out_size, void* d_ws, size_t ws_size,
                              hipStream_t stream) {
  (void)in_sizes; (void)n_in; (void)out_size;
  const float* feat  = (const float*)d_in[0];
  const float* props = (const float*)d_in[1];
  const float* convw[3] = {(const float*)d_in[2], (const float*)d_in[6], (const float*)d_in[10]};
  const float* bng[3]   = {(const float*)d_in[4], (const float*)d_in[8], (const float*)d_in[12]};
  const float* bnb[3]   = {(const float*)d_in[5], (const float*)d_in[9], (const float*)d_in[13]};
  const float* fcw  = (const float*)d_in[14];
  const float* fcg  = (const float*)d_in[16];
  const float* fcbb = (const float*)d_in[17];
  const float* iw   = (const float*)d_in[18];
  const float* ib   = (const float*)d_in[19];
  float* out = (float*)d_out;

  char* w = (char*)d_ws;
  size_t off = 0;
  auto take = [&](size_t sz) -> char* { char* p = w + off; off += (sz + 255) & ~(size_t)255; return p; };
  const size_t SZ_XP = (size_t)NIMG * PPIX * CDIM * 2;
  const size_t SZ_YB = (size_t)NIMG * NPX * CDIM * 2;   // bf16 y
  const size_t SZ_P  = (size_t)SBLK * 256 * 4;          // partial stats (one array)
  bf16*  xp0 = (bf16*)take(SZ_XP);
  bf16*  xp1 = (bf16*)take(SZ_XP);
  bf16*  y   = (bf16*)take(SZ_YB);
  bf16*  wball = (bf16*)take((size_t)3 * NWC * 2);
  bf16*  fwb = (bf16*)take((size_t)CDIM * FCK * 2);
  bf16*  rfb = (bf16*)take((size_t)NROI * FCK * 2);
  float* fcx = (float*)take((size_t)NROI * CDIM * 4);
  float* fcp = (float*)take((size_t)8 * NROI * CDIM * 4);
  float* psum = (float*)take(SZ_P);
  float* psq  = (float*)take(SZ_P);
  float* scsh = (float*)take(8 * 256 * 4);
  if (off > ws_size) return;  // workspace too small: fail loudly

  k_halo<<<dim3(NIMG, 2), 256, 0, stream>>>(xp0, xp1);
  k_prep<<<dim3((3 * NWC + CDIM * FCK + 255) / 256), 256, 0, stream>>>(
      convw[0], convw[1], convw[2], fcw, wball, fwb);
  k_convert<<<dim3(HH, NIMG), 256, 0, stream>>>(feat, xp0);

  for (int l = 0; l < 3; ++l) {
    bf16* xin = (l == 1) ? xp1 : xp0;           // conv1<-xp0, conv2<-xp1, conv3<-xp0
    bf16* wbl = wball + (size_t)l * NWC;
    k_conv<<<dim3(704), 256, 0, stream>>>(xin, wbl, y);
    k_statsb<<<dim3(SBLK), 256, 0, stream>>>(y, psum, psq);
    float* sc = scsh + l * 512; float* sh = sc + 256;
    k_sredfin<<<dim3(1), 1024, 0, stream>>>(psum, psq, bng[l], bnb[l], sc, sh, 1.f / 41472.f);
    if (l < 2) {
      bf16* xo = (l == 0) ? xp1 : xp0;
      k_normalize<<<dim3(NPX / 8, NIMG), 256, 0, stream>>>(y, sc, sh, xo);
    }
  }
  float* sc3 = scsh + 2 * 512; float* sh3 = sc3 + 256;
  k_pool<<<dim3(NROI, 2, 2), 128, 0, stream>>>(y, sc3, sh3, props, rfb);
  k_fcgemm<<<dim3(8, 4, 8), 256, 0, stream>>>(rfb, fwb, fcp);
  k_fcred<<<dim3(NROI), 256, 0, stream>>>(fcp, fcx);
  float* fsc = scsh + 3 * 512; float* fsh = fsc + 256;
  k_fcstatfin<<<dim3(1), 1024, 0, stream>>>(fcx, fcg, fcbb, fsc, fsh);
  k_iou<<<dim3(NROI), 256, 0, stream>>>(fcx, fsc, fsh, iw, ib, out);
}